// Round 5
// baseline (180.783 us; speedup 1.0000x reference)
//
#include <hip/hip_runtime.h>
#include <hip/hip_bf16.h>
#include <math.h>

typedef __attribute__((ext_vector_type(8))) short short8v;
typedef __attribute__((ext_vector_type(4))) float float4v;

#define TB 64   // targets per block (4 waves x 16 targets)

__device__ __forceinline__ short f2bf(float f) {
    __hip_bfloat16 h = __float2bfloat16(f);
    short s; __builtin_memcpy(&s, &h, sizeof(short));
    return s;
}
__device__ __forceinline__ float4v mfma_bf16(short8v a, short8v b, float4v c) {
    return __builtin_amdgcn_mfma_f32_16x16x32_bf16(a, b, c, 0, 0, 0);
}

// wT swizzle: spreads rows (stride-4 writes were 8-way conflicted) across banks;
// xor at 8-u16 granularity keeps ds_read_b128 alignment.
__device__ __forceinline__ int WTI(int row, int col) {
    return row * 72 + (col ^ ((((row) >> 2) & 7) << 3));
}

__global__ __launch_bounds__(256)
void copy_x_kernel(const float4* __restrict__ x, float4* __restrict__ out, int n4) {
    int i = blockIdx.x * blockDim.x + threadIdx.x;
    if (i < n4) out[i] = x[i];
}

// Block = 256 threads (4 waves), TB=64 targets; wave owns 16 targets = 128 point
// rows = 8 m-tiles of mfma_16x16x32. Softmax: feat_px part + sm_b are
// segment-constant -> cancel; logits = ptx@sm_w[:64] via B col-tile 4 with smw
// broadcast to ALL 16 columns (logit lane-local, no shuffles).
// ptx_out = ptx@W1 + q[t], q = fpx@W2 + fo_b (q_lds overlays dead fpx/wT).
// Main loop is 2-stage pipelined: epilogue(mt-1) runs under load/MFMA of mt.
__global__ __launch_bounds__(256, 4)
void fused_kernel(const float* __restrict__ x,
                  const float* __restrict__ ptx,
                  const float* __restrict__ sm_w,
                  const float* __restrict__ fo_w,
                  const float* __restrict__ fo_b,
                  const int* __restrict__ point_key,
                  const int* __restrict__ pixel_tgt_idx,
                  float* __restrict__ xout,
                  float* __restrict__ ptx_out,
                  int n_tgt, int n_pts, int hw)
{
    // phase 1: fpx[64][72]u16 (9216B) + wT[128][72]u16 (18432B)  = 27648B
    // phase 2 overlay: q_lds[64][68]f32 (17408B) + agg[64][68]f32 (17408B)
    __shared__ __align__(16) char sraw[34816];
    unsigned short (*fpx)[72] = (unsigned short (*)[72])sraw;
    unsigned short* wTf       = (unsigned short*)(sraw + 9216);
    float (*q_lds)[68]        = (float (*)[68])sraw;
    float (*agg)[68]          = (float (*)[68])(sraw + 17408);
    __shared__ int pix_s[TB], r0_s[TB], deg_s[TB];

    const int tid  = threadIdx.x;
    const int lane = tid & 63;
    const int w    = tid >> 6;
    const int lo16 = lane & 15;
    const int g    = lane >> 4;
    const int t0   = blockIdx.x * TB;
    const int tw0  = w * 16;              // wave's first local target

    // ---- S0: issue weight loads early ----
    float4 wv[8];
    {
        const float4* fw4 = (const float4*)fo_w;   // 2048 float4, coalesced
        #pragma unroll
        for (int i = 0; i < 8; ++i) wv[i] = fw4[i * 256 + tid];
    }
    if (tid < TB) {
        int t = t0 + tid;
        bool v = t < n_tgt;
        int r0 = v ? point_key[t] : 0;
        int d  = v ? (point_key[t + 1] - r0) : 0;
        pix_s[tid] = v ? pixel_tgt_idx[t] : 0;
        r0_s[tid]  = r0;
        deg_s[tid] = d > 8 ? 8 : d;
    }
    float fb[4];
    #pragma unroll
    for (int ct = 0; ct < 4; ++ct) fb[ct] = fo_b[ct * 16 + lo16];

    // ---- S1: wT staging (bf16, transposed [cout|cin_px][k], swizzled) ----
    #pragma unroll
    for (int i = 0; i < 8; ++i) {
        int flat = (i * 256 + tid) * 4;
        int k = flat >> 6, c = flat & 63;
        int wrow0 = (k & 64) + c;          // W1 -> rows 0..63, W2 -> 64..127
        int col = k & 63;
        wTf[WTI(wrow0 + 0, col)] = (unsigned short)f2bf(wv[i].x);
        wTf[WTI(wrow0 + 1, col)] = (unsigned short)f2bf(wv[i].y);
        wTf[WTI(wrow0 + 2, col)] = (unsigned short)f2bf(wv[i].z);
        wTf[WTI(wrow0 + 3, col)] = (unsigned short)f2bf(wv[i].w);
    }
    __syncthreads();   // meta + wT visible

    // ---- pgm: point-row indices for all 8 m-tiles (off the load critical path) ----
    int pgm[8];
    #pragma unroll
    for (int mt = 0; mt < 8; ++mt) {
        int tlA = tw0 + mt * 2 + (lo16 >> 3);
        int pg  = r0_s[tlA] + (lo16 & 7);
        pgm[mt] = pg < n_pts ? pg : n_pts - 1;
    }

    // ---- S2: fpx gather (4 threads/target, coalesced per channel plane) ----
    {
        const int tgt = tid >> 2, q4 = tid & 3;
        const int pix = pix_s[tgt];
        const float* xp = x + (size_t)(q4 * 16) * hw + pix;
        #pragma unroll
        for (int hhalf = 0; hhalf < 2; ++hhalf) {
            short8v pk;
            #pragma unroll
            for (int j = 0; j < 8; ++j)
                pk[j] = f2bf(xp[(size_t)(hhalf * 8 + j) * hw]);
            *(short8v*)&fpx[tgt][q4 * 16 + hhalf * 8] = pk;
        }
    }

    // B1 fragments: [W1 cols | smw-broadcast], 5 col-tiles x 2 K-halves
    short8v b1[5][2];
    #pragma unroll
    for (int ct = 0; ct < 4; ++ct)
        #pragma unroll
        for (int kh = 0; kh < 2; ++kh)
            b1[ct][kh] = *(const short8v*)&wTf[WTI(ct * 16 + lo16, kh * 32 + g * 8)];
    #pragma unroll
    for (int kh = 0; kh < 2; ++kh) {       // smw in EVERY column -> lane-local logits
        short8v bb;
        #pragma unroll
        for (int j = 0; j < 8; ++j)
            bb[j] = f2bf(sm_w[kh * 32 + g * 8 + j]);
        b1[4][kh] = bb;
    }

    // ---- first A-tile load, issued before the q-GEMM phase for cover ----
    float4 lb0, lb1, lb2, lb3;
    {
        const float* prow = ptx + (size_t)pgm[0] * 64 + g * 8;
        lb0 = *(const float4*)(prow);
        lb1 = *(const float4*)(prow + 4);
        lb2 = *(const float4*)(prow + 32);
        lb3 = *(const float4*)(prow + 36);
    }
    __syncthreads();   // fpx visible

    // ---- S3: q-GEMM (wave's 16 targets) ----
    float4v qv4[4];
    {
        short8v a20 = *(const short8v*)&fpx[tw0 + lo16][g * 8];
        short8v a21 = *(const short8v*)&fpx[tw0 + lo16][32 + g * 8];
        #pragma unroll
        for (int ct = 0; ct < 4; ++ct) {
            short8v b20 = *(const short8v*)&wTf[WTI(64 + ct * 16 + lo16, g * 8)];
            short8v b21 = *(const short8v*)&wTf[WTI(64 + ct * 16 + lo16, 32 + g * 8)];
            float4v z = {0.f, 0.f, 0.f, 0.f};
            z = mfma_bf16(a20, b20, z);
            qv4[ct] = mfma_bf16(a21, b21, z);
        }
    }
    __syncthreads();   // all waves done with fpx/wT -> overlays live
    #pragma unroll
    for (int ct = 0; ct < 4; ++ct)
        #pragma unroll
        for (int r = 0; r < 4; ++r)
            q_lds[tw0 + g * 4 + r][ct * 16 + lo16] = qv4[ct][r] + fb[ct];
    // wave-local rows -> no barrier

    // ---- S4: main loop, 2-stage pipeline (epilogue deferred one tile) ----
    float4v cfr[2][5];

    auto EPIL = [&](int mt, const float4v* c) {
        const int tE   = tw0 + mt * 2 + (g >> 1);
        const int degE = deg_s[tE];
        const int r0E  = r0_s[tE];
        float lgt[4];
        #pragma unroll
        for (int r = 0; r < 4; ++r)
            lgt[r] = (((g & 1) * 4 + r) < degE) ? c[4][r] : -3.4e38f;
        float m4 = fmaxf(fmaxf(lgt[0], lgt[1]), fmaxf(lgt[2], lgt[3]));
        float m8 = fmaxf(m4, __shfl_xor(m4, 16));
        float wgt[4], wsum = 0.f;
        #pragma unroll
        for (int r = 0; r < 4; ++r) {
            int pE = (g & 1) * 4 + r;
            wgt[r] = (pE < degE) ? __expf(lgt[r] - m8) : 0.0f;
            wsum += wgt[r];
        }
        wsum += __shfl_xor(wsum, 16);
        const float inv = 1.0f / (wsum + 1e-16f);
        #pragma unroll
        for (int ct = 0; ct < 4; ++ct) {
            const int col = ct * 16 + lo16;
            const float qv = q_lds[tE][col];
            float ap = 0.f;
            #pragma unroll
            for (int r = 0; r < 4; ++r) {
                float po = c[ct][r] + qv;
                int pE = (g & 1) * 4 + r;
                if (pE < degE)
                    ptx_out[(size_t)(r0E + pE) * 64 + col] = po;
                ap = fmaf(wgt[r] * inv, po, ap);
            }
            ap += __shfl_xor(ap, 16);
            if (!(lane & 16)) agg[tE][col] = ap;   // groups 0,2 hold both targets
        }
    };

    #pragma unroll
    for (int mt = 0; mt < 8; ++mt) {
        // convert current tile (consumes lb*)
        short8v a0, a1;
        a0[0] = f2bf(lb0.x); a0[1] = f2bf(lb0.y); a0[2] = f2bf(lb0.z); a0[3] = f2bf(lb0.w);
        a0[4] = f2bf(lb1.x); a0[5] = f2bf(lb1.y); a0[6] = f2bf(lb1.z); a0[7] = f2bf(lb1.w);
        a1[0] = f2bf(lb2.x); a1[1] = f2bf(lb2.y); a1[2] = f2bf(lb2.z); a1[3] = f2bf(lb2.w);
        a1[4] = f2bf(lb3.x); a1[5] = f2bf(lb3.y); a1[6] = f2bf(lb3.z); a1[7] = f2bf(lb3.w);

        if (mt < 7) {   // prefetch next tile; consumed next iteration
            const float* prow = ptx + (size_t)pgm[mt + 1] * 64 + g * 8;
            lb0 = *(const float4*)(prow);
            lb1 = *(const float4*)(prow + 4);
            lb2 = *(const float4*)(prow + 32);
            lb3 = *(const float4*)(prow + 36);
        }

        #pragma unroll
        for (int ct = 0; ct < 5; ++ct) {
            float4v z = {0.f, 0.f, 0.f, 0.f};
            z = mfma_bf16(a0, b1[ct][0], z);
            cfr[mt & 1][ct] = mfma_bf16(a1, b1[ct][1], z);
        }

        if (mt > 0) EPIL(mt - 1, cfr[(mt - 1) & 1]);   // hidden under this tile
    }
    EPIL(7, cfr[1]);
    __syncthreads();

    // ---- S5: xout write-back (4 threads/target, coalesced per channel plane) ----
    {
        const int tgt = tid >> 2, q4 = tid & 3;
        if (t0 + tgt < n_tgt) {
            const int pix = pix_s[tgt];
            float* xp = xout + (size_t)(q4 * 16) * hw + pix;
            #pragma unroll
            for (int u = 0; u < 4; ++u) {
                float4 v = *(const float4*)&agg[tgt][q4 * 16 + u * 4];
                xp[(size_t)(u * 4 + 0) * hw] = v.x;
                xp[(size_t)(u * 4 + 1) * hw] = v.y;
                xp[(size_t)(u * 4 + 2) * hw] = v.z;
                xp[(size_t)(u * 4 + 3) * hw] = v.w;
            }
        }
    }
}

extern "C" void kernel_launch(void* const* d_in, const int* in_sizes, int n_in,
                              void* d_out, int out_size, void* d_ws, size_t ws_size,
                              hipStream_t stream) {
    const float* x             = (const float*)d_in[0];
    const float* ptx           = (const float*)d_in[1];
    const float* sm_w          = (const float*)d_in[2];
    // d_in[3] = sm_b: segment-constant logit shift, cancels in softmax
    const float* fo_w          = (const float*)d_in[4];
    const float* fo_b          = (const float*)d_in[5];
    const int*   point_key     = (const int*)d_in[6];
    const int*   pixel_tgt_idx = (const int*)d_in[7];

    const int x_elems = in_sizes[0];          // 64 * H * W
    const int hw      = x_elems / 64;
    const int n_tgt   = in_sizes[7];
    const int n_pts   = in_sizes[1] / 64;

    float* xout    = (float*)d_out;
    float* ptx_out = xout + (size_t)x_elems;

    const int n4 = x_elems / 4;
    copy_x_kernel<<<(n4 + 255) / 256, 256, 0, stream>>>(
        (const float4*)x, (float4*)xout, n4);

    const int blocks = (n_tgt + TB - 1) / TB;
    fused_kernel<<<blocks, 256, 0, stream>>>(
        x, ptx, sm_w, fo_w, fo_b, point_key, pixel_tgt_idx,
        xout, ptx_out, n_tgt, n_pts, hw);
}

// Round 6
// 171.222 us; speedup vs baseline: 1.0558x; 1.0558x over previous
//
#include <hip/hip_runtime.h>
#include <hip/hip_bf16.h>
#include <math.h>

typedef __attribute__((ext_vector_type(8))) short short8v;
typedef __attribute__((ext_vector_type(4))) float float4v;

#define TB 64   // targets per block (4 waves x 16 targets)

__device__ __forceinline__ short f2bf(float f) {
    __hip_bfloat16 h = __float2bfloat16(f);
    short s; __builtin_memcpy(&s, &h, sizeof(short));
    return s;
}
__device__ __forceinline__ float4v mfma_bf16(short8v a, short8v b, float4v c) {
    return __builtin_amdgcn_mfma_f32_16x16x32_bf16(a, b, c, 0, 0, 0);
}

// wT swizzle: staging writes (16 lanes, stride-4 rows) were 8-way bank-conflicted;
// xor at 8-u16 granularity keeps ds_read_b128 alignment. Verified -3M conflicts (r5).
__device__ __forceinline__ int WTI(int row, int col) {
    return row * 72 + (col ^ (((row >> 2) & 7) << 3));
}

__global__ __launch_bounds__(256)
void copy_x_kernel(const float4* __restrict__ x, float4* __restrict__ out, int n4) {
    int i = blockIdx.x * blockDim.x + threadIdx.x;
    if (i < n4) out[i] = x[i];
}

// Block = 256 threads (4 waves), TB=64 targets; wave owns 16 targets = 128 point
// rows = 8 m-tiles of mfma_16x16x32. Softmax: feat_px part + sm_b are
// segment-constant -> cancel; logits = ptx@sm_w[:64] via B col-tile 4 with smw
// broadcast to ALL 16 columns (logits lane-local, no shuffles).
// ptx_out = ptx@W1 + q[t], q = fpx@W2 + fo_b (q_lds overlays dead fpx/wT).
// Main loop 2-stage pipelined; fragments in NAMED regs passed BY VALUE (r5's
// pointer-arg lambda put them in scratch: FETCH +116MB / WRITE +72MB).
__global__ __launch_bounds__(256, 4)
void fused_kernel(const float* __restrict__ x,
                  const float* __restrict__ ptx,
                  const float* __restrict__ sm_w,
                  const float* __restrict__ fo_w,
                  const float* __restrict__ fo_b,
                  const int* __restrict__ point_key,
                  const int* __restrict__ pixel_tgt_idx,
                  float* __restrict__ xout,
                  float* __restrict__ ptx_out,
                  int n_tgt, int n_pts, int hw)
{
    // phase 1: fpx[64][72]u16 (9216B) + wT[128][72]u16 (18432B)
    // phase 2 overlay: q_lds[64][68]f32 (17408B) + agg[64][68]f32 (17408B)
    __shared__ __align__(16) char sraw[34816];
    unsigned short (*fpx)[72] = (unsigned short (*)[72])sraw;
    unsigned short* wTf       = (unsigned short*)(sraw + 9216);
    float (*q_lds)[68]        = (float (*)[68])sraw;
    float (*agg)[68]          = (float (*)[68])(sraw + 17408);
    __shared__ int pix_s[TB], r0_s[TB], deg_s[TB];

    const int tid  = threadIdx.x;
    const int lane = tid & 63;
    const int w    = tid >> 6;
    const int lo16 = lane & 15;
    const int g    = lane >> 4;
    const int t0   = blockIdx.x * TB;
    const int tw0  = w * 16;              // wave's first local target

    // ---- S0: issue weight loads early ----
    float4 wv[8];
    {
        const float4* fw4 = (const float4*)fo_w;   // 2048 float4, coalesced
        #pragma unroll
        for (int i = 0; i < 8; ++i) wv[i] = fw4[i * 256 + tid];
    }
    if (tid < TB) {
        int t = t0 + tid;
        bool v = t < n_tgt;
        int r0 = v ? point_key[t] : 0;
        int d  = v ? (point_key[t + 1] - r0) : 0;
        pix_s[tid] = v ? pixel_tgt_idx[t] : 0;
        r0_s[tid]  = r0;
        deg_s[tid] = d > 8 ? 8 : d;
    }
    float fb[4];
    #pragma unroll
    for (int ct = 0; ct < 4; ++ct) fb[ct] = fo_b[ct * 16 + lo16];

    // ---- S1: wT staging (bf16, transposed [cout|cin_px][k], swizzled) ----
    #pragma unroll
    for (int i = 0; i < 8; ++i) {
        int flat = (i * 256 + tid) * 4;
        int k = flat >> 6, c = flat & 63;
        int wrow0 = (k & 64) + c;          // W1 -> rows 0..63, W2 -> 64..127
        int col = k & 63;
        wTf[WTI(wrow0 + 0, col)] = (unsigned short)f2bf(wv[i].x);
        wTf[WTI(wrow0 + 1, col)] = (unsigned short)f2bf(wv[i].y);
        wTf[WTI(wrow0 + 2, col)] = (unsigned short)f2bf(wv[i].z);
        wTf[WTI(wrow0 + 3, col)] = (unsigned short)f2bf(wv[i].w);
    }
    __syncthreads();   // meta + wT visible

    // ---- pgm: point-row indices for all 8 m-tiles (off the load critical path) ----
    int pgm[8];
    #pragma unroll
    for (int mt = 0; mt < 8; ++mt) {
        int tlA = tw0 + mt * 2 + (lo16 >> 3);
        int pg  = r0_s[tlA] + (lo16 & 7);
        pgm[mt] = pg < n_pts ? pg : n_pts - 1;
    }

    // ---- S2: fpx gather (4 threads/target, coalesced per channel plane) ----
    {
        const int tgt = tid >> 2, q4 = tid & 3;
        const int pix = pix_s[tgt];
        const float* xp = x + (size_t)(q4 * 16) * hw + pix;
        #pragma unroll
        for (int hhalf = 0; hhalf < 2; ++hhalf) {
            short8v pk;
            #pragma unroll
            for (int j = 0; j < 8; ++j)
                pk[j] = f2bf(xp[(size_t)(hhalf * 8 + j) * hw]);
            *(short8v*)&fpx[tgt][q4 * 16 + hhalf * 8] = pk;
        }
    }

    // B1 fragments: [W1 cols | smw-broadcast], 5 col-tiles x 2 K-halves
    short8v b1[5][2];
    #pragma unroll
    for (int ct = 0; ct < 4; ++ct)
        #pragma unroll
        for (int kh = 0; kh < 2; ++kh)
            b1[ct][kh] = *(const short8v*)&wTf[WTI(ct * 16 + lo16, kh * 32 + g * 8)];
    #pragma unroll
    for (int kh = 0; kh < 2; ++kh) {       // smw in EVERY column -> lane-local logits
        short8v bb;
        #pragma unroll
        for (int j = 0; j < 8; ++j)
            bb[j] = f2bf(sm_w[kh * 32 + g * 8 + j]);
        b1[4][kh] = bb;
    }

    // ---- first A-tile load, issued before the q-GEMM phase for cover ----
    float4 lb0, lb1, lb2, lb3;
    {
        const float* prow = ptx + (size_t)pgm[0] * 64 + g * 8;
        lb0 = *(const float4*)(prow);
        lb1 = *(const float4*)(prow + 4);
        lb2 = *(const float4*)(prow + 32);
        lb3 = *(const float4*)(prow + 36);
    }
    __syncthreads();   // fpx visible

    // ---- S3: q-GEMM (wave's 16 targets) ----
    float4v qv4[4];
    {
        short8v a20 = *(const short8v*)&fpx[tw0 + lo16][g * 8];
        short8v a21 = *(const short8v*)&fpx[tw0 + lo16][32 + g * 8];
        #pragma unroll
        for (int ct = 0; ct < 4; ++ct) {
            short8v b20 = *(const short8v*)&wTf[WTI(64 + ct * 16 + lo16, g * 8)];
            short8v b21 = *(const short8v*)&wTf[WTI(64 + ct * 16 + lo16, 32 + g * 8)];
            float4v z = {0.f, 0.f, 0.f, 0.f};
            z = mfma_bf16(a20, b20, z);
            qv4[ct] = mfma_bf16(a21, b21, z);
        }
    }
    __syncthreads();   // all waves done with fpx/wT -> overlays live
    #pragma unroll
    for (int ct = 0; ct < 4; ++ct)
        #pragma unroll
        for (int r = 0; r < 4; ++r)
            q_lds[tw0 + g * 4 + r][ct * 16 + lo16] = qv4[ct][r] + fb[ct];
    // wave-local rows -> no barrier

    // ---- epilogue: fragments BY VALUE (keeps them in VGPRs) ----
    auto EPIL = [&](int mt, float4v e0, float4v e1, float4v e2, float4v e3, float4v e4) {
        const int tE   = tw0 + mt * 2 + (g >> 1);
        const int degE = deg_s[tE];
        const int r0E  = r0_s[tE];
        float lgt[4];
        #pragma unroll
        for (int r = 0; r < 4; ++r)
            lgt[r] = (((g & 1) * 4 + r) < degE) ? e4[r] : -3.4e38f;
        float m4 = fmaxf(fmaxf(lgt[0], lgt[1]), fmaxf(lgt[2], lgt[3]));
        float m8 = fmaxf(m4, __shfl_xor(m4, 16));
        float wgt[4], wsum = 0.f;
        #pragma unroll
        for (int r = 0; r < 4; ++r) {
            int pE = (g & 1) * 4 + r;
            wgt[r] = (pE < degE) ? __expf(lgt[r] - m8) : 0.0f;
            wsum += wgt[r];
        }
        wsum += __shfl_xor(wsum, 16);
        const float inv = 1.0f / (wsum + 1e-16f);
        #pragma unroll
        for (int ct = 0; ct < 4; ++ct) {
            float4v ec = (ct == 0) ? e0 : (ct == 1) ? e1 : (ct == 2) ? e2 : e3;
            const int col = ct * 16 + lo16;
            const float qv = q_lds[tE][col];
            float ap = 0.f;
            #pragma unroll
            for (int r = 0; r < 4; ++r) {
                float po = ec[r] + qv;
                int pE = (g & 1) * 4 + r;
                if (pE < degE)
                    ptx_out[(size_t)(r0E + pE) * 64 + col] = po;
                ap = fmaf(wgt[r] * inv, po, ap);
            }
            ap += __shfl_xor(ap, 16);
            if (!(lane & 16)) agg[tE][col] = ap;   // groups 0,2 hold both targets
        }
    };

    // ---- S4: main loop, 2-stage pipeline with named fragment registers ----
    float4v p0, p1, p2, p3, p4;
    #pragma unroll
    for (int mt = 0; mt < 8; ++mt) {
        short8v a0, a1;
        a0[0] = f2bf(lb0.x); a0[1] = f2bf(lb0.y); a0[2] = f2bf(lb0.z); a0[3] = f2bf(lb0.w);
        a0[4] = f2bf(lb1.x); a0[5] = f2bf(lb1.y); a0[6] = f2bf(lb1.z); a0[7] = f2bf(lb1.w);
        a1[0] = f2bf(lb2.x); a1[1] = f2bf(lb2.y); a1[2] = f2bf(lb2.z); a1[3] = f2bf(lb2.w);
        a1[4] = f2bf(lb3.x); a1[5] = f2bf(lb3.y); a1[6] = f2bf(lb3.z); a1[7] = f2bf(lb3.w);

        if (mt < 7) {   // prefetch next tile; consumed next iteration
            const float* prow = ptx + (size_t)pgm[mt + 1] * 64 + g * 8;
            lb0 = *(const float4*)(prow);
            lb1 = *(const float4*)(prow + 4);
            lb2 = *(const float4*)(prow + 32);
            lb3 = *(const float4*)(prow + 36);
        }

        float4v z = {0.f, 0.f, 0.f, 0.f};
        float4v n0 = mfma_bf16(a1, b1[0][1], mfma_bf16(a0, b1[0][0], z));
        float4v n1 = mfma_bf16(a1, b1[1][1], mfma_bf16(a0, b1[1][0], z));
        float4v n2 = mfma_bf16(a1, b1[2][1], mfma_bf16(a0, b1[2][0], z));
        float4v n3 = mfma_bf16(a1, b1[3][1], mfma_bf16(a0, b1[3][0], z));
        float4v n4 = mfma_bf16(a1, b1[4][1], mfma_bf16(a0, b1[4][0], z));

        if (mt > 0) EPIL(mt - 1, p0, p1, p2, p3, p4);   // hidden under this tile
        p0 = n0; p1 = n1; p2 = n2; p3 = n3; p4 = n4;
    }
    EPIL(7, p0, p1, p2, p3, p4);
    __syncthreads();

    // ---- S5: xout write-back (4 threads/target, coalesced per channel plane) ----
    {
        const int tgt = tid >> 2, q4 = tid & 3;
        if (t0 + tgt < n_tgt) {
            const int pix = pix_s[tgt];
            float* xp = xout + (size_t)(q4 * 16) * hw + pix;
            #pragma unroll
            for (int u = 0; u < 4; ++u) {
                float4 v = *(const float4*)&agg[tgt][q4 * 16 + u * 4];
                xp[(size_t)(u * 4 + 0) * hw] = v.x;
                xp[(size_t)(u * 4 + 1) * hw] = v.y;
                xp[(size_t)(u * 4 + 2) * hw] = v.z;
                xp[(size_t)(u * 4 + 3) * hw] = v.w;
            }
        }
    }
}

extern "C" void kernel_launch(void* const* d_in, const int* in_sizes, int n_in,
                              void* d_out, int out_size, void* d_ws, size_t ws_size,
                              hipStream_t stream) {
    const float* x             = (const float*)d_in[0];
    const float* ptx           = (const float*)d_in[1];
    const float* sm_w          = (const float*)d_in[2];
    // d_in[3] = sm_b: segment-constant logit shift, cancels in softmax
    const float* fo_w          = (const float*)d_in[4];
    const float* fo_b          = (const float*)d_in[5];
    const int*   point_key     = (const int*)d_in[6];
    const int*   pixel_tgt_idx = (const int*)d_in[7];

    const int x_elems = in_sizes[0];          // 64 * H * W
    const int hw      = x_elems / 64;
    const int n_tgt   = in_sizes[7];
    const int n_pts   = in_sizes[1] / 64;

    float* xout    = (float*)d_out;
    float* ptx_out = xout + (size_t)x_elems;

    const int n4 = x_elems / 4;
    copy_x_kernel<<<(n4 + 255) / 256, 256, 0, stream>>>(
        (const float4*)x, (float4*)xout, n4);

    const int blocks = (n_tgt + TB - 1) / TB;
    fused_kernel<<<blocks, 256, 0, stream>>>(
        x, ptx, sm_w, fo_w, fo_b, point_key, pixel_tgt_idx,
        xout, ptx_out, n_tgt, n_pts, hw);
}

// Round 7
// 136.982 us; speedup vs baseline: 1.3198x; 1.2500x over previous
//
#include <hip/hip_runtime.h>
#include <hip/hip_bf16.h>
#include <math.h>

typedef __attribute__((ext_vector_type(8))) short short8v;
typedef __attribute__((ext_vector_type(4))) float float4v;

#define TB 64   // targets per block (4 waves x 16 targets)

__device__ __forceinline__ short f2bf(float f) {
    __hip_bfloat16 h = __float2bfloat16(f);
    short s; __builtin_memcpy(&s, &h, sizeof(short));
    return s;
}
__device__ __forceinline__ float4v mfma_bf16(short8v a, short8v b, float4v c) {
    return __builtin_amdgcn_mfma_f32_16x16x32_bf16(a, b, c, 0, 0, 0);
}

// wT swizzle: staging writes (16 lanes, stride-4 rows) were 8-way bank-conflicted;
// xor at 8-u16 granularity keeps ds_read_b128 alignment. Verified -3M conflicts (r5).
__device__ __forceinline__ int WTI(int row, int col) {
    return row * 72 + (col ^ (((row >> 2) & 7) << 3));
}

__global__ __launch_bounds__(256)
void copy_x_kernel(const float4* __restrict__ x, float4* __restrict__ out, int n4) {
    int i = blockIdx.x * blockDim.x + threadIdx.x;
    if (i < n4) out[i] = x[i];
}

// Block = 256 threads (4 waves), TB=64 targets; wave owns 16 targets = 128 point
// rows = 8 m-tiles. OPERAND-SWAPPED MFMA: A = weights (row = cout), B = points
// (col = point). Same registers, same loads as the row-major variant, but the
// C layout becomes [cout-quad x point]: each lane holds 4 CONSECUTIVE channels
// of ONE point -> dwordx4 ptx_out stores (16 scalar stores -> 4 vector stores),
// 1 exp per lane (was 4), octet-butterfly softmax.
// Softmax: feat_px part + sm_b segment-constant -> cancel; logits = ptx@sm_w[:64]
// via A-tile 4 = smw broadcast to all rows (logit lane-local per point).
// ptx_out = ptx@W1 + q[t], q = fpx@W2 + fo_b (q_lds overlays dead fpx/wT).
__global__ __launch_bounds__(256, 4)
void fused_kernel(const float* __restrict__ x,
                  const float* __restrict__ ptx,
                  const float* __restrict__ sm_w,
                  const float* __restrict__ fo_w,
                  const float* __restrict__ fo_b,
                  const int* __restrict__ point_key,
                  const int* __restrict__ pixel_tgt_idx,
                  float* __restrict__ xout,
                  float* __restrict__ ptx_out,
                  int n_tgt, int n_pts, int hw)
{
    // phase 1: fpx[64][72]u16 (9216B) + wT[128][72]u16 (18432B) = 27648B
    // phase 2 overlay: q_lds[64][68]f32 (17408B) + agg[64][68]f32 (17408B)
    __shared__ __align__(16) char sraw[34816];
    unsigned short (*fpx)[72] = (unsigned short (*)[72])sraw;
    unsigned short* wTf       = (unsigned short*)(sraw + 9216);
    float (*q_lds)[68]        = (float (*)[68])sraw;
    float (*agg)[68]          = (float (*)[68])(sraw + 17408);
    __shared__ int pix_s[TB], r0_s[TB], deg_s[TB];

    const int tid  = threadIdx.x;
    const int lane = tid & 63;
    const int w    = tid >> 6;
    const int lo16 = lane & 15;
    const int g    = lane >> 4;
    const int t0   = blockIdx.x * TB;
    const int tw0  = w * 16;              // wave's first local target

    // ---- S0: issue weight + bias loads early ----
    float4 wv[8];
    {
        const float4* fw4 = (const float4*)fo_w;   // 2048 float4, coalesced
        #pragma unroll
        for (int i = 0; i < 8; ++i) wv[i] = fw4[i * 256 + tid];
    }
    float4 fb40 = *(const float4*)&fo_b[ 0 + g * 4];
    float4 fb41 = *(const float4*)&fo_b[16 + g * 4];
    float4 fb42 = *(const float4*)&fo_b[32 + g * 4];
    float4 fb43 = *(const float4*)&fo_b[48 + g * 4];
    if (tid < TB) {
        int t = t0 + tid;
        bool v = t < n_tgt;
        int r0 = v ? point_key[t] : 0;
        int d  = v ? (point_key[t + 1] - r0) : 0;
        pix_s[tid] = v ? pixel_tgt_idx[t] : 0;
        r0_s[tid]  = r0;
        deg_s[tid] = d > 8 ? 8 : d;
    }

    // ---- S1: wT staging (bf16, transposed [cout|cin_px][k], swizzled) ----
    #pragma unroll
    for (int i = 0; i < 8; ++i) {
        int flat = (i * 256 + tid) * 4;
        int k = flat >> 6, c = flat & 63;
        int wrow0 = (k & 64) + c;          // W1 -> rows 0..63, W2 -> 64..127
        int col = k & 63;
        wTf[WTI(wrow0 + 0, col)] = (unsigned short)f2bf(wv[i].x);
        wTf[WTI(wrow0 + 1, col)] = (unsigned short)f2bf(wv[i].y);
        wTf[WTI(wrow0 + 2, col)] = (unsigned short)f2bf(wv[i].z);
        wTf[WTI(wrow0 + 3, col)] = (unsigned short)f2bf(wv[i].w);
    }
    __syncthreads();   // meta + wT visible

    // ---- pgm: point-row indices for all 8 m-tiles ----
    int pgm[8];
    #pragma unroll
    for (int mt = 0; mt < 8; ++mt) {
        int tlA = tw0 + mt * 2 + (lo16 >> 3);
        int pg  = r0_s[tlA] + (lo16 & 7);
        pgm[mt] = pg < n_pts ? pg : n_pts - 1;
    }

    // ---- S2: fpx gather (4 threads/target, coalesced per channel plane) ----
    {
        const int tgt = tid >> 2, q4 = tid & 3;
        const int pix = pix_s[tgt];
        const float* xp = x + (size_t)(q4 * 16) * hw + pix;
        #pragma unroll
        for (int hhalf = 0; hhalf < 2; ++hhalf) {
            short8v pk;
            #pragma unroll
            for (int j = 0; j < 8; ++j)
                pk[j] = f2bf(xp[(size_t)(hhalf * 8 + j) * hw]);
            *(short8v*)&fpx[tgt][q4 * 16 + hhalf * 8] = pk;
        }
    }

    // weight fragments (now the A operand: row = cout): [W1 | smw-broadcast]
    short8v b1[5][2];
    #pragma unroll
    for (int ct = 0; ct < 4; ++ct)
        #pragma unroll
        for (int kh = 0; kh < 2; ++kh)
            b1[ct][kh] = *(const short8v*)&wTf[WTI(ct * 16 + lo16, kh * 32 + g * 8)];
    #pragma unroll
    for (int kh = 0; kh < 2; ++kh) {       // smw in EVERY row -> logit lane-local
        short8v bb;
        #pragma unroll
        for (int j = 0; j < 8; ++j)
            bb[j] = f2bf(sm_w[kh * 32 + g * 8 + j]);
        b1[4][kh] = bb;
    }

    // ---- first point-tile load, issued before the q-GEMM phase for cover ----
    float4 lb0, lb1, lb2, lb3;
    {
        const float* prow = ptx + (size_t)pgm[0] * 64 + g * 8;
        lb0 = *(const float4*)(prow);
        lb1 = *(const float4*)(prow + 4);
        lb2 = *(const float4*)(prow + 32);
        lb3 = *(const float4*)(prow + 36);
    }
    __syncthreads();   // fpx visible

    // ---- S3: q-GEMM swapped (A = W2 rows, B = fpx cols -> q[cout][target]) ----
    float4v qv4[4];
    {
        short8v a20 = *(const short8v*)&fpx[tw0 + lo16][g * 8];        // B: col=target
        short8v a21 = *(const short8v*)&fpx[tw0 + lo16][32 + g * 8];
        #pragma unroll
        for (int ct = 0; ct < 4; ++ct) {
            short8v b20 = *(const short8v*)&wTf[WTI(64 + ct * 16 + lo16, g * 8)];
            short8v b21 = *(const short8v*)&wTf[WTI(64 + ct * 16 + lo16, 32 + g * 8)];
            float4v z = {0.f, 0.f, 0.f, 0.f};
            z = mfma_bf16(b20, a20, z);          // A = weights
            qv4[ct] = mfma_bf16(b21, a21, z);
        }
    }
    __syncthreads();   // all waves done with fpx/wT -> overlays live
    // lane (lo16=T, g) holds q[T][ct*16+g*4+r] -> b128 store, wave-local rows
    {
        float4v t0v = qv4[0]; t0v[0] += fb40.x; t0v[1] += fb40.y; t0v[2] += fb40.z; t0v[3] += fb40.w;
        float4v t1v = qv4[1]; t1v[0] += fb41.x; t1v[1] += fb41.y; t1v[2] += fb41.z; t1v[3] += fb41.w;
        float4v t2v = qv4[2]; t2v[0] += fb42.x; t2v[1] += fb42.y; t2v[2] += fb42.z; t2v[3] += fb42.w;
        float4v t3v = qv4[3]; t3v[0] += fb43.x; t3v[1] += fb43.y; t3v[2] += fb43.z; t3v[3] += fb43.w;
        *(float4v*)&q_lds[tw0 + lo16][ 0 + g * 4] = t0v;
        *(float4v*)&q_lds[tw0 + lo16][16 + g * 4] = t1v;
        *(float4v*)&q_lds[tw0 + lo16][32 + g * 4] = t2v;
        *(float4v*)&q_lds[tw0 + lo16][48 + g * 4] = t3v;
    }

// per-channel-tile epilogue on NAMED regs (no arrays -> no scratch)
#define EPIL_CT(CT, CREG)                                                      \
    {                                                                          \
        const int colb = (CT) * 16 + g * 4;                                    \
        const float4 q4 = *(const float4*)&q_lds[tE][colb];                    \
        float4v po;                                                            \
        po[0] = CREG[0] + q4.x; po[1] = CREG[1] + q4.y;                        \
        po[2] = CREG[2] + q4.z; po[3] = CREG[3] + q4.w;                        \
        if (val)                                                               \
            *(float4v*)&ptx_out[(size_t)(r0E + pE) * 64 + colb] = po;          \
        float s0 = po[0] * wn, s1 = po[1] * wn, s2 = po[2] * wn, s3 = po[3] * wn; \
        s0 += __shfl_xor(s0, 1); s1 += __shfl_xor(s1, 1);                      \
        s2 += __shfl_xor(s2, 1); s3 += __shfl_xor(s3, 1);                      \
        s0 += __shfl_xor(s0, 2); s1 += __shfl_xor(s1, 2);                      \
        s2 += __shfl_xor(s2, 2); s3 += __shfl_xor(s3, 2);                      \
        s0 += __shfl_xor(s0, 4); s1 += __shfl_xor(s1, 4);                      \
        s2 += __shfl_xor(s2, 4); s3 += __shfl_xor(s3, 4);                      \
        if (pE == 0) {                                                         \
            float4v ag; ag[0] = s0; ag[1] = s1; ag[2] = s2; ag[3] = s3;        \
            *(float4v*)&agg[tE][colb] = ag;                                    \
        }                                                                      \
    }

    // ---- S4: main loop, 8 m-tiles, depth-1 prefetch, inline epilogue ----
    #pragma unroll
    for (int mt = 0; mt < 8; ++mt) {
        short8v a0, a1;   // B operand: col = point
        a0[0] = f2bf(lb0.x); a0[1] = f2bf(lb0.y); a0[2] = f2bf(lb0.z); a0[3] = f2bf(lb0.w);
        a0[4] = f2bf(lb1.x); a0[5] = f2bf(lb1.y); a0[6] = f2bf(lb1.z); a0[7] = f2bf(lb1.w);
        a1[0] = f2bf(lb2.x); a1[1] = f2bf(lb2.y); a1[2] = f2bf(lb2.z); a1[3] = f2bf(lb2.w);
        a1[4] = f2bf(lb3.x); a1[5] = f2bf(lb3.y); a1[6] = f2bf(lb3.z); a1[7] = f2bf(lb3.w);

        if (mt < 7) {   // prefetch next tile
            const float* prow = ptx + (size_t)pgm[mt + 1] * 64 + g * 8;
            lb0 = *(const float4*)(prow);
            lb1 = *(const float4*)(prow + 4);
            lb2 = *(const float4*)(prow + 32);
            lb3 = *(const float4*)(prow + 36);
        }

        float4v z = {0.f, 0.f, 0.f, 0.f};
        float4v cc0 = mfma_bf16(b1[0][1], a1, mfma_bf16(b1[0][0], a0, z));
        float4v cc1 = mfma_bf16(b1[1][1], a1, mfma_bf16(b1[1][0], a0, z));
        float4v cc2 = mfma_bf16(b1[2][1], a1, mfma_bf16(b1[2][0], a0, z));
        float4v cc3 = mfma_bf16(b1[3][1], a1, mfma_bf16(b1[3][0], a0, z));
        float4v cc4 = mfma_bf16(b1[4][1], a1, mfma_bf16(b1[4][0], a0, z));

        // lane owns point pE of target tE; logit = cc4[0] (rows identical)
        const int tE   = tw0 + mt * 2 + (lo16 >> 3);
        const int degE = deg_s[tE];
        const int r0E  = r0_s[tE];
        const int pE   = lo16 & 7;
        const bool val = (pE < degE);

        float lg = val ? cc4[0] : -3.4e38f;
        float mx = lg;
        mx = fmaxf(mx, __shfl_xor(mx, 1));
        mx = fmaxf(mx, __shfl_xor(mx, 2));
        mx = fmaxf(mx, __shfl_xor(mx, 4));
        float e = val ? __expf(lg - mx) : 0.0f;
        float sm = e;
        sm += __shfl_xor(sm, 1);
        sm += __shfl_xor(sm, 2);
        sm += __shfl_xor(sm, 4);
        const float wn = e / (sm + 1e-16f);

        EPIL_CT(0, cc0)
        EPIL_CT(1, cc1)
        EPIL_CT(2, cc2)
        EPIL_CT(3, cc3)
    }
#undef EPIL_CT
    __syncthreads();

    // ---- S5: xout write-back (4 threads/target, coalesced per channel plane) ----
    {
        const int tgt = tid >> 2, q4 = tid & 3;
        if (t0 + tgt < n_tgt) {
            const int pix = pix_s[tgt];
            float* xp = xout + (size_t)(q4 * 16) * hw + pix;
            #pragma unroll
            for (int u = 0; u < 4; ++u) {
                float4 v = *(const float4*)&agg[tgt][q4 * 16 + u * 4];
                xp[(size_t)(u * 4 + 0) * hw] = v.x;
                xp[(size_t)(u * 4 + 1) * hw] = v.y;
                xp[(size_t)(u * 4 + 2) * hw] = v.z;
                xp[(size_t)(u * 4 + 3) * hw] = v.w;
            }
        }
    }
}

extern "C" void kernel_launch(void* const* d_in, const int* in_sizes, int n_in,
                              void* d_out, int out_size, void* d_ws, size_t ws_size,
                              hipStream_t stream) {
    const float* x             = (const float*)d_in[0];
    const float* ptx           = (const float*)d_in[1];
    const float* sm_w          = (const float*)d_in[2];
    // d_in[3] = sm_b: segment-constant logit shift, cancels in softmax
    const float* fo_w          = (const float*)d_in[4];
    const float* fo_b          = (const float*)d_in[5];
    const int*   point_key     = (const int*)d_in[6];
    const int*   pixel_tgt_idx = (const int*)d_in[7];

    const int x_elems = in_sizes[0];          // 64 * H * W
    const int hw      = x_elems / 64;
    const int n_tgt   = in_sizes[7];
    const int n_pts   = in_sizes[1] / 64;

    float* xout    = (float*)d_out;
    float* ptx_out = xout + (size_t)x_elems;

    const int n4 = x_elems / 4;
    copy_x_kernel<<<(n4 + 255) / 256, 256, 0, stream>>>(
        (const float4*)x, (float4*)xout, n4);

    const int blocks = (n_tgt + TB - 1) / TB;
    fused_kernel<<<blocks, 256, 0, stream>>>(
        x, ptx, sm_w, fo_w, fo_b, point_key, pixel_tgt_idx,
        xout, ptx_out, n_tgt, n_pts, hw);
}